// Round 1
// baseline (66120.251 us; speedup 1.0000x reference)
//
#include <hip/hip_runtime.h>
#include <stdint.h>

typedef __bf16 bf16;
typedef __bf16 bf16x8 __attribute__((ext_vector_type(8)));
typedef __bf16 bf16x4 __attribute__((ext_vector_type(4)));
typedef float f32x4 __attribute__((ext_vector_type(4)));

enum { EPI_PLAIN = 0, EPI_TANH = 1, EPI_K1 = 2, EPI_K23 = 3, EPI_K4 = 4 };

// Stage a 64x64 f32 tile (rows row0..row0+63, cols kt..kt+63 of a [.,ld] matrix)
// into split hi/lo bf16 LDS tiles with XOR-chunk swizzle:
//   elem(r,k) -> r*64 + (((k>>3)^(r&7))<<3) + (k&7)
// Optionally fuses A = base + alpha * kbase (kbase is [.,512] f32).
template<bool HASK>
__device__ __forceinline__ void stage_tile(const float* __restrict__ base, long ld,
                                           int row0, int kt,
                                           const float* __restrict__ kbase, float alpha,
                                           bf16* __restrict__ hi, bf16* __restrict__ lo,
                                           int tid)
{
    const int tr = tid >> 4;          // 0..15
    const int c4 = (tid & 15) << 2;   // 0,4,...,60
#pragma unroll
    for (int p = 0; p < 4; ++p) {
        const int r = tr + (p << 4);
        f32x4 v = *(const f32x4*)(base + (long)(row0 + r) * ld + (kt + c4));
        if (HASK) {
            const f32x4 kv = *(const f32x4*)(kbase + (long)(row0 + r) * 512 + (kt + c4));
            v = v + alpha * kv;
        }
        const int idx = (r << 6) + (((c4 >> 3) ^ (r & 7)) << 3) + (c4 & 7);
        bf16x4 hv, lv;
#pragma unroll
        for (int j = 0; j < 4; ++j) {
            const float x = v[j];
            const bf16 hb = (bf16)x;          // RNE
            const float rem = x - (float)hb;  // exact in f32
            hv[j] = hb;
            lv[j] = (bf16)rem;
        }
        *(bf16x4*)(hi + idx) = hv;
        *(bf16x4*)(lo + idx) = lv;
    }
}

// C[M,N] = epi( A[M,K] @ W[N,K]^T + bias ),  split-bf16 MFMA, f32 accumulate.
// BM=BN=BK=64, 256 threads (4 waves, 2x2), wave tile 32x32 = 2x2 frags of 16x16x32.
// EPI_PLAIN: C = v
// EPI_TANH : C = tanhf(v)           (prologue may fuse A = A + acoef*dt * Kin)
// EPI_K1   : C = v; ksum = v
// EPI_K23  : C = v; ksum += 2v
// EPI_K4   : hbuf += (dt/24) * (ksum + v)
template<int EPI, bool HASK>
__global__ __launch_bounds__(256)
void gemm_k(const float* __restrict__ A, long lda,
            const float* __restrict__ Kin,
            const float* __restrict__ W, long ldb,
            const float* __restrict__ bias,
            float* __restrict__ C, long ldc,
            float* __restrict__ ksum,
            float* __restrict__ hbuf,
            int Kdim,
            const float* __restrict__ tarr, int step, float acoef)
{
    __shared__ __align__(16) bf16 Ahi[64 * 64];
    __shared__ __align__(16) bf16 Alo[64 * 64];
    __shared__ __align__(16) bf16 Bhi[64 * 64];
    __shared__ __align__(16) bf16 Blo[64 * 64];

    const int tid = threadIdx.x;
    const int m0 = blockIdx.x * 64;
    const int n0 = blockIdx.y * 64;

    float dt = 0.f;
    if (tarr) dt = tarr[step] - tarr[step - 1];
    const float alpha = acoef * dt;

    const int lane = tid & 63;
    const int wid  = tid >> 6;
    const int wm = (wid >> 1) * 32;   // wave row offset in tile
    const int wn = (wid & 1) * 32;    // wave col offset in tile

    f32x4 acc[2][2] = {};

    for (int kt = 0; kt < Kdim; kt += 64) {
        stage_tile<HASK>(A, lda, m0, kt, Kin, alpha, Ahi, Alo, tid);
        stage_tile<false>(W, ldb, n0, kt, nullptr, 0.f, Bhi, Blo, tid);
        __syncthreads();
#pragma unroll
        for (int k0 = 0; k0 < 2; ++k0) {   // two K=32 MFMA steps per LDS tile
            bf16x8 ah[2], al[2], bh[2], bl[2];
#pragma unroll
            for (int i = 0; i < 2; ++i) {
                const int ar = wm + i * 16 + (lane & 15);
                const int ac = ((k0 << 2) + (lane >> 4)) ^ (ar & 7);
                ah[i] = *(const bf16x8*)(Ahi + (ar << 6) + (ac << 3));
                al[i] = *(const bf16x8*)(Alo + (ar << 6) + (ac << 3));
                const int br = wn + i * 16 + (lane & 15);
                const int bc = ((k0 << 2) + (lane >> 4)) ^ (br & 7);
                bh[i] = *(const bf16x8*)(Bhi + (br << 6) + (bc << 3));
                bl[i] = *(const bf16x8*)(Blo + (br << 6) + (bc << 3));
            }
#pragma unroll
            for (int mi = 0; mi < 2; ++mi)
#pragma unroll
                for (int ni = 0; ni < 2; ++ni) {
                    acc[mi][ni] = __builtin_amdgcn_mfma_f32_16x16x32_bf16(ah[mi], bh[ni], acc[mi][ni], 0, 0, 0);
                    acc[mi][ni] = __builtin_amdgcn_mfma_f32_16x16x32_bf16(al[mi], bh[ni], acc[mi][ni], 0, 0, 0);
                    acc[mi][ni] = __builtin_amdgcn_mfma_f32_16x16x32_bf16(ah[mi], bl[ni], acc[mi][ni], 0, 0, 0);
                }
        }
        __syncthreads();
    }

    const float hk = dt * (1.0f / 24.0f);   // hs/6 with hs = dt/4
#pragma unroll
    for (int mi = 0; mi < 2; ++mi)
#pragma unroll
        for (int ni = 0; ni < 2; ++ni) {
            const int col = n0 + wn + ni * 16 + (lane & 15);
            const float bv = bias[col];
#pragma unroll
            for (int rg = 0; rg < 4; ++rg) {
                const int row = m0 + wm + mi * 16 + ((lane >> 4) << 2) + rg;
                float v = acc[mi][ni][rg] + bv;
                if (EPI == EPI_TANH) v = tanhf(v);
                if (EPI == EPI_PLAIN || EPI == EPI_TANH) {
                    C[(long)row * ldc + col] = v;
                } else {
                    const long ko = (long)row * 512 + col;
                    if (EPI == EPI_K1)       { C[ko] = v; ksum[ko] = v; }
                    else if (EPI == EPI_K23) { C[ko] = v; ksum[ko] += 2.0f * v; }
                    else                     { hbuf[ko] += hk * (ksum[ko] + v); }
                }
            }
        }
}

// GRU gate combine: h = (1-z)*n + z*h  with r,z,n from gi/gh [B,1536] slices.
__global__ __launch_bounds__(256)
void gru_gate(const float* __restrict__ gi, const float* __restrict__ gh,
              float* __restrict__ h)
{
    const int idx = blockIdx.x * 256 + threadIdx.x;   // 0 .. 1024*512-1
    const int b = idx >> 9;
    const int j = idx & 511;
    const long gb = (long)b * 1536;
    const float r = 1.f / (1.f + __expf(-(gi[gb + j]        + gh[gb + j])));
    const float z = 1.f / (1.f + __expf(-(gi[gb + 512 + j]  + gh[gb + 512 + j])));
    const float n = tanhf(gi[gb + 1024 + j] + r * gh[gb + 1024 + j]);
    const long ho = (long)b * 512 + j;
    h[ho] = (1.f - z) * n + z * h[ho];
}

extern "C" void kernel_launch(void* const* d_in, const int* in_sizes, int n_in,
                              void* d_out, int out_size, void* d_ws, size_t ws_size,
                              hipStream_t stream)
{
    (void)in_sizes; (void)n_in; (void)out_size; (void)ws_size;
    const float* x   = (const float*)d_in[0];
    const float* t   = (const float*)d_in[1];
    const float* Wih = (const float*)d_in[2];
    const float* Whh = (const float*)d_in[3];
    const float* bih = (const float*)d_in[4];
    const float* bhh = (const float*)d_in[5];
    const float* W1  = (const float*)d_in[6];
    const float* b1  = (const float*)d_in[7];
    const float* W2  = (const float*)d_in[8];
    const float* b2  = (const float*)d_in[9];
    const float* Wmu = (const float*)d_in[10];
    const float* bmu = (const float*)d_in[11];
    const float* Wlv = (const float*)d_in[12];
    const float* blv = (const float*)d_in[13];
    float* out = (float*)d_out;

    char* wsb = (char*)d_ws;
    float* h    = (float*)(wsb + 0);             // [1024,512]  2MB
    float* tmp  = (float*)(wsb + (2l << 20));    // [1024,512]  2MB
    float* kbuf = (float*)(wsb + (4l << 20));    // [1024,512]  2MB
    float* ksum = (float*)(wsb + (6l << 20));    // [1024,512]  2MB
    float* gi   = (float*)(wsb + (8l << 20));    // [1024,1536] 6MB
    float* gh   = (float*)(wsb + (14l << 20));   // [1024,1536] 6MB

    const int B = 1024, T = 128, I = 128, H = 512;

    hipMemsetAsync(h, 0, (size_t)B * H * sizeof(float), stream);

    auto gru = [&](int s) {
        gemm_k<EPI_PLAIN, false><<<dim3(B / 64, 1536 / 64), 256, 0, stream>>>(
            x + (long)s * I, (long)T * I, nullptr, Wih, I, bih, gi, 1536,
            nullptr, nullptr, I, nullptr, 0, 0.f);
        gemm_k<EPI_PLAIN, false><<<dim3(B / 64, 1536 / 64), 256, 0, stream>>>(
            h, H, nullptr, Whh, H, bhh, gh, 1536,
            nullptr, nullptr, H, nullptr, 0, 0.f);
        gru_gate<<<dim3(B * H / 256), 256, 0, stream>>>(gi, gh, h);
    };

    gru(0);  // h0 = GRU(x[:,0,:], 0)   (gh with h=0 yields bhh, matching ref)

    for (int s = 1; s < T; ++s) {
        for (int sub = 0; sub < 4; ++sub) {
            // k1 = f(h)
            gemm_k<EPI_TANH, false><<<dim3(16, 8), 256, 0, stream>>>(
                h, H, nullptr, W1, H, b1, tmp, H, nullptr, nullptr, H, nullptr, 0, 0.f);
            gemm_k<EPI_K1, false><<<dim3(16, 8), 256, 0, stream>>>(
                tmp, H, nullptr, W2, H, b2, kbuf, H, ksum, nullptr, H, nullptr, 0, 0.f);
            // k2 = f(h + 0.5*hs*k1),  0.5*hs = dt/8
            gemm_k<EPI_TANH, true><<<dim3(16, 8), 256, 0, stream>>>(
                h, H, kbuf, W1, H, b1, tmp, H, nullptr, nullptr, H, t, s, 0.125f);
            gemm_k<EPI_K23, false><<<dim3(16, 8), 256, 0, stream>>>(
                tmp, H, nullptr, W2, H, b2, kbuf, H, ksum, nullptr, H, nullptr, 0, 0.f);
            // k3 = f(h + 0.5*hs*k2)
            gemm_k<EPI_TANH, true><<<dim3(16, 8), 256, 0, stream>>>(
                h, H, kbuf, W1, H, b1, tmp, H, nullptr, nullptr, H, t, s, 0.125f);
            gemm_k<EPI_K23, false><<<dim3(16, 8), 256, 0, stream>>>(
                tmp, H, nullptr, W2, H, b2, kbuf, H, ksum, nullptr, H, nullptr, 0, 0.f);
            // k4 = f(h + hs*k3),  hs = dt/4 ; then h += (hs/6)*(k1+2k2+2k3+k4)
            gemm_k<EPI_TANH, true><<<dim3(16, 8), 256, 0, stream>>>(
                h, H, kbuf, W1, H, b1, tmp, H, nullptr, nullptr, H, t, s, 0.25f);
            gemm_k<EPI_K4, false><<<dim3(16, 8), 256, 0, stream>>>(
                tmp, H, nullptr, W2, H, b2, kbuf, H, ksum, h, H, t, s, 0.f);
        }
        gru(s);
    }

    // mu / logvar projections into d_out (mu first, then logvar)
    gemm_k<EPI_PLAIN, false><<<dim3(16, 1), 256, 0, stream>>>(
        h, H, nullptr, Wmu, H, bmu, out, 64, nullptr, nullptr, H, nullptr, 0, 0.f);
    gemm_k<EPI_PLAIN, false><<<dim3(16, 1), 256, 0, stream>>>(
        h, H, nullptr, Wlv, H, blv, out + (long)B * 64, 64, nullptr, nullptr, H, nullptr, 0, 0.f);
}

// Round 2
// 42436.154 us; speedup vs baseline: 1.5581x; 1.5581x over previous
//
#include <hip/hip_runtime.h>
#include <stdint.h>

typedef __bf16 bf16;
typedef __bf16 bf16x8 __attribute__((ext_vector_type(8)));
typedef float f32x4 __attribute__((ext_vector_type(4)));

// ---------------------------------------------------------------------------
// Weight pre-pack: f32 [N,K] row-major -> split hi/lo bf16 in MFMA B-frag
// streaming layout: pk[half][nf][ks][lane][8],  lane = (n&15) | (((k&31)>>3)<<4),
// ks = k>>5, e = k&7.  One 16B load per (lane, nf, ks, half), fully coalesced.
// ---------------------------------------------------------------------------
__global__ void pack_split(const float* __restrict__ src, bf16* __restrict__ dst,
                           int N, int K, int NFtot, int nfBase)
{
    int gid = blockIdx.x * 256 + threadIdx.x;
    if (gid >= N * K) return;
    int n = gid / K, k = gid - n * K;
    int KS = K >> 5;
    float x = src[gid];
    bf16 hb = (bf16)x;                    // RNE
    bf16 lb = (bf16)(x - (float)hb);      // residual (exact in f32)
    int nf = nfBase + (n >> 4);
    int l  = (n & 15) | (((k & 31) >> 3) << 4);
    int ks = k >> 5;
    int e  = k & 7;
    int base = ((nf * KS + ks) << 9) + (l << 3) + e;
    int half = NFtot * KS * 512;
    dst[base] = hb;
    dst[half + base] = lb;
}

// ---------------------------------------------------------------------------
// Streamed split-bf16 MFMA:  acc[i] += A(16x512 from LDS S) * Wfrag(nf_i)
// 3-term split: hi*hi + lo*hi + hi*lo  (f32 accumulate)
// S layout: [half][ks][lane][8] bf16 (half stride 8192 elems)
// ---------------------------------------------------------------------------
template<int NFR, int KS, int NFtot, int STRIDE>
__device__ __forceinline__ void mm_stream(const bf16* __restrict__ pk, int nf0, int lane,
                                          const bf16* __restrict__ S, f32x4* acc)
{
    const int halfoff = NFtot * KS * 512;
#pragma unroll
    for (int i = 0; i < NFR; ++i) { f32x4 z = {0.f, 0.f, 0.f, 0.f}; acc[i] = z; }
#pragma unroll 2
    for (int ks = 0; ks < KS; ++ks) {
        bf16x8 ah = *(const bf16x8*)(S + ((ks << 6) + lane) * 8);
        bf16x8 al = *(const bf16x8*)(S + 8192 + ((ks << 6) + lane) * 8);
#pragma unroll
        for (int i = 0; i < NFR; ++i) {
            int nf = (i >> 1) * STRIDE + nf0 + (i & 1);
            const bf16* pb = pk + ((nf * KS + ks) << 9) + (lane << 3);
            bf16x8 bh = *(const bf16x8*)pb;
            bf16x8 bl = *(const bf16x8*)(pb + halfoff);
            acc[i] = __builtin_amdgcn_mfma_f32_16x16x32_bf16(ah, bh, acc[i], 0, 0, 0);
            acc[i] = __builtin_amdgcn_mfma_f32_16x16x32_bf16(al, bh, acc[i], 0, 0, 0);
            acc[i] = __builtin_amdgcn_mfma_f32_16x16x32_bf16(ah, bl, acc[i], 0, 0, 0);
        }
    }
}

// Same, with A-frags from registers (K=128 x-input for the GRU gi GEMM)
template<int NFR, int NFtot, int STRIDE>
__device__ __forceinline__ void mm_stream_x(const bf16* __restrict__ pk, int nf0, int lane,
                                            const bf16x8* xh, const bf16x8* xl, f32x4* acc)
{
    const int KS = 4;
    const int halfoff = NFtot * KS * 512;
#pragma unroll
    for (int i = 0; i < NFR; ++i) { f32x4 z = {0.f, 0.f, 0.f, 0.f}; acc[i] = z; }
#pragma unroll
    for (int ks = 0; ks < 4; ++ks) {
#pragma unroll
        for (int i = 0; i < NFR; ++i) {
            int nf = (i >> 1) * STRIDE + nf0 + (i & 1);
            const bf16* pb = pk + ((nf * KS + ks) << 9) + (lane << 3);
            bf16x8 bh = *(const bf16x8*)pb;
            bf16x8 bl = *(const bf16x8*)(pb + halfoff);
            acc[i] = __builtin_amdgcn_mfma_f32_16x16x32_bf16(xh[ks], bh, acc[i], 0, 0, 0);
            acc[i] = __builtin_amdgcn_mfma_f32_16x16x32_bf16(xl[ks], bh, acc[i], 0, 0, 0);
            acc[i] = __builtin_amdgcn_mfma_f32_16x16x32_bf16(xh[ks], bl, acc[i], 0, 0, 0);
        }
    }
}

// scatter one f32 value (tile row r in [0,16), col c in [0,512)) into split LDS S
__device__ __forceinline__ void scat(bf16* __restrict__ Sp, int r, int c, float v)
{
    bf16 hb = (bf16)v;
    bf16 lb = (bf16)(v - (float)hb);
    int off = (((c >> 5) << 6) + (r | (((c & 31) >> 3) << 4))) * 8 + (c & 7);
    Sp[off] = hb;
    Sp[8192 + off] = lb;
}

// ---------------------------------------------------------------------------
// Persistent kernel: 64 blocks x 1024 threads (16 waves). Block owns 16 batch
// rows; h lives in LDS for the whole 128-step recurrence. Zero grid sync.
// ---------------------------------------------------------------------------
__global__ __launch_bounds__(1024, 4)
void odegru_persist(const float* __restrict__ x, const float* __restrict__ t,
                    const float* __restrict__ bih, const float* __restrict__ bhh,
                    const float* __restrict__ b1,  const float* __restrict__ b2,
                    const float* __restrict__ bmu, const float* __restrict__ blv,
                    const bf16* __restrict__ pkW1, const bf16* __restrict__ pkW2,
                    const bf16* __restrict__ pkWhh, const bf16* __restrict__ pkWih,
                    const bf16* __restrict__ pkWout, float* __restrict__ out)
{
    __shared__ float hbuf[16 * 512];        // h, f32 [row][col]      (32 KB)
    __shared__ bf16  S[2 * 16 * 64 * 8];    // split operand buffer   (32 KB)

    const int tid  = threadIdx.x;
    const int lane = tid & 63;
    const int w    = tid >> 6;              // wave 0..15
    const int li   = lane & 15, lh = lane >> 4;
    const int m0   = blockIdx.x << 4;       // batch-row base
    const int Tn = 128, In = 128;

    const int c0 = (w << 5) + li;           // wave's first output col + lane col
    const int rb = lh << 2;                 // C-frag row base

    float b1c[2], b2c[2], bihr[2], bihz[2], bihn[2], bhhr[2], bhhz[2], bhhn[2];
#pragma unroll
    for (int fi = 0; fi < 2; ++fi) {
        int c = c0 + (fi << 4);
        b1c[fi] = b1[c];  b2c[fi] = b2[c];
        bihr[fi] = bih[c]; bihz[fi] = bih[512 + c]; bihn[fi] = bih[1024 + c];
        bhhr[fi] = bhh[c]; bhhz[fi] = bhh[512 + c]; bhhn[fi] = bhh[1024 + c];
    }

    f32x4 acc[2];
    float ksum[2][4];
    f32x4 giacc[6], ghacc[6];

    for (int s = 0; s < 128; ++s) {
        const float dt = (s > 0) ? (t[s] - t[s - 1]) : 0.f;
        if (s > 0) {
            const float a01 = dt * 0.125f, a2 = dt * 0.25f, hk = dt * (1.f / 24.f);
#pragma unroll 1
            for (int sub = 0; sub < 4; ++sub) {
#pragma unroll 1
                for (int st = 0; st < 4; ++st) {
                    // phase A: tmp_pre = A @ W1^T   (A-split in S)
                    mm_stream<2, 16, 32, 0>(pkW1, w << 1, lane, S, acc);
                    __syncthreads();
                    // phase B: S = split(tanh(tmp_pre + b1))
#pragma unroll
                    for (int fi = 0; fi < 2; ++fi)
#pragma unroll
                        for (int rg = 0; rg < 4; ++rg)
                            scat(S, rb + rg, c0 + (fi << 4), tanhf(acc[fi][rg] + b1c[fi]));
                    __syncthreads();
                    // phase C: k = tmp @ W2^T
                    mm_stream<2, 16, 32, 0>(pkW2, w << 1, lane, S, acc);
                    __syncthreads();
                    // phase D: RK4 combine; S = split(next A) or split(new h)
                    const float al = (st < 2) ? a01 : a2;
#pragma unroll
                    for (int fi = 0; fi < 2; ++fi)
#pragma unroll
                        for (int rg = 0; rg < 4; ++rg) {
                            float v = acc[fi][rg] + b2c[fi];
                            int c = c0 + (fi << 4);
                            int hoff = (rb + rg) * 512 + c;
                            if (st == 0) ksum[fi][rg] = v;
                            else if (st < 3) ksum[fi][rg] += 2.f * v;
                            float nv;
                            if (st < 3) {
                                nv = hbuf[hoff] + al * v;
                            } else {
                                nv = hbuf[hoff] + hk * (ksum[fi][rg] + v);
                                hbuf[hoff] = nv;
                            }
                            scat(S, rb + rg, c, nv);
                        }
                    __syncthreads();
                }
            }
        }
        // phase E: gi = x_s @ Wih^T  (x-frags in regs; no LDS use)
        bf16x8 xh[4], xl[4];
        {
            const float* xp = x + ((long)(m0 + li) * Tn + s) * In + (lh << 3);
#pragma unroll
            for (int ks = 0; ks < 4; ++ks) {
                f32x4 v0 = *(const f32x4*)(xp + (ks << 5));
                f32x4 v1 = *(const f32x4*)(xp + (ks << 5) + 4);
                bf16x8 h8, l8;
#pragma unroll
                for (int j = 0; j < 4; ++j) {
                    bf16 hb = (bf16)v0[j]; h8[j] = hb;     l8[j] = (bf16)(v0[j] - (float)hb);
                    bf16 h2 = (bf16)v1[j]; h8[4 + j] = h2; l8[4 + j] = (bf16)(v1[j] - (float)h2);
                }
                xh[ks] = h8; xl[ks] = l8;
            }
        }
        mm_stream_x<6, 96, 32>(pkWih, w << 1, lane, xh, xl, giacc);
        // phase F: gh = h @ Whh^T  (S still holds split(h))
        if (s > 0) {
            mm_stream<6, 16, 96, 32>(pkWhh, w << 1, lane, S, ghacc);
        } else {
#pragma unroll
            for (int i = 0; i < 6; ++i) { f32x4 z = {0.f, 0.f, 0.f, 0.f}; ghacc[i] = z; }
        }
        __syncthreads();
        // phase G: GRU gates; h <- (1-z)*n + z*h; S = split(h_new)
#pragma unroll
        for (int fi = 0; fi < 2; ++fi)
#pragma unroll
            for (int rg = 0; rg < 4; ++rg) {
                int c = c0 + (fi << 4);
                int hoff = (rb + rg) * 512 + c;
                float gr = giacc[fi][rg] + bihr[fi] + ghacc[fi][rg] + bhhr[fi];
                float gz = giacc[2 + fi][rg] + bihz[fi] + ghacc[2 + fi][rg] + bhhz[fi];
                float rr = 1.f / (1.f + __expf(-gr));
                float zz = 1.f / (1.f + __expf(-gz));
                float nn = tanhf(giacc[4 + fi][rg] + bihn[fi] + rr * (ghacc[4 + fi][rg] + bhhn[fi]));
                float hold = (s > 0) ? hbuf[hoff] : 0.f;
                float hn = (1.f - zz) * nn + zz * hold;
                hbuf[hoff] = hn;
                scat(S, rb + rg, c, hn);
            }
        __syncthreads();
    }
    // final: mu / logvar projections (S = split(h_T))
    if (w < 8) {
        f32x4 oacc[1];
        mm_stream<1, 16, 8, 0>(pkWout, w, lane, S, oacc);
        const float* bo = (w < 4) ? bmu : blv;
        int cl = ((w & 3) << 4) + li;
        float bv = bo[cl];
        float* ob = out + ((w < 4) ? 0 : 65536);
#pragma unroll
        for (int rg = 0; rg < 4; ++rg)
            ob[(long)(m0 + rb + rg) * 64 + cl] = oacc[0][rg] + bv;
    }
}

extern "C" void kernel_launch(void* const* d_in, const int* in_sizes, int n_in,
                              void* d_out, int out_size, void* d_ws, size_t ws_size,
                              hipStream_t stream)
{
    (void)in_sizes; (void)n_in; (void)out_size; (void)ws_size;
    const float* x   = (const float*)d_in[0];
    const float* t   = (const float*)d_in[1];
    const float* Wih = (const float*)d_in[2];
    const float* Whh = (const float*)d_in[3];
    const float* bih = (const float*)d_in[4];
    const float* bhh = (const float*)d_in[5];
    const float* W1  = (const float*)d_in[6];
    const float* b1  = (const float*)d_in[7];
    const float* W2  = (const float*)d_in[8];
    const float* b2  = (const float*)d_in[9];
    const float* Wmu = (const float*)d_in[10];
    const float* bmu = (const float*)d_in[11];
    const float* Wlv = (const float*)d_in[12];
    const float* blv = (const float*)d_in[13];
    float* out = (float*)d_out;

    bf16* pk1  = (bf16*)d_ws;             // 2*512*512   = 524288 elems (1 MB)
    bf16* pk2  = pk1 + 524288;            // 1 MB
    bf16* pkhh = pk2 + 524288;            // 2*1536*512  = 1572864 (3 MB)
    bf16* pkih = pkhh + 1572864;          // 2*1536*128  = 393216 (0.75 MB)
    bf16* pkout = pkih + 393216;          // 2*128*512   = 131072 (0.25 MB)

    pack_split<<<1024, 256, 0, stream>>>(W1,  pk1,  512, 512, 32, 0);
    pack_split<<<1024, 256, 0, stream>>>(W2,  pk2,  512, 512, 32, 0);
    pack_split<<<3072, 256, 0, stream>>>(Whh, pkhh, 1536, 512, 96, 0);
    pack_split<<<768,  256, 0, stream>>>(Wih, pkih, 1536, 128, 96, 0);
    pack_split<<<128,  256, 0, stream>>>(Wmu, pkout, 64, 512, 8, 0);
    pack_split<<<128,  256, 0, stream>>>(Wlv, pkout, 64, 512, 8, 4);

    odegru_persist<<<64, 1024, 0, stream>>>(x, t, bih, bhh, b1, b2, bmu, blv,
                                            pk1, pk2, pkhh, pkih, pkout, out);
}